// Round 4
// baseline (341.261 us; speedup 1.0000x reference)
//
#include <hip/hip_runtime.h>
#include <cstdint>
#include <cstddef>

typedef __bf16 bf16;
typedef __bf16 bf16x8 __attribute__((ext_vector_type(8)));
typedef float floatx4 __attribute__((ext_vector_type(4)));
typedef float floatx8 __attribute__((ext_vector_type(8)));
typedef unsigned int u32;

constexpr int Bb = 4, Ll = 4096, Dd = 1024;
constexpr int M  = Bb * Ll;          // 16384 rows
constexpr int NC = 64, CT = 64;      // chunks per sequence, chunk length

// async 16B global->LDS (width=16 emits global_load_lds_dwordx4)
typedef const __attribute__((address_space(1))) u32 glb_u32;
typedef __attribute__((address_space(3))) u32 lds_u32;
__device__ __forceinline__ void gld16(const bf16* g, bf16* l) {
  __builtin_amdgcn_global_load_lds((glb_u32*)g, (lds_u32*)l, 16, 0, 0);
}
// raw barrier (no vmcnt drain) + compiler memory fence
__device__ __forceinline__ void bar() {
  __builtin_amdgcn_s_barrier();
  asm volatile("" ::: "memory");
}

// ---------------- W f32 -> bf16 converts ----------------
__global__ __launch_bounds__(256) void convw(
    const float* __restrict__ W, bf16* __restrict__ Wb)
{
  size_t base = ((size_t)blockIdx.x * 256 + threadIdx.x) * 8;
  floatx8 w = *(const floatx8*)(W + base);
  bf16x8 o;
  #pragma unroll
  for (int j = 0; j < 8; ++j) o[j] = (bf16)w[j];
  *(bf16x8*)(Wb + base) = o;
}

__global__ __launch_bounds__(256) void convw3(
    const float* __restrict__ Wa, const float* __restrict__ Wbp, const float* __restrict__ Wc,
    bf16* __restrict__ oa, bf16* __restrict__ ob, bf16* __restrict__ oc)
{
  const float* s = blockIdx.y == 0 ? Wa : (blockIdx.y == 1 ? Wbp : Wc);
  bf16*        d = blockIdx.y == 0 ? oa : (blockIdx.y == 1 ? ob  : oc);
  size_t base = ((size_t)blockIdx.x * 256 + threadIdx.x) * 8;
  floatx8 w = *(const floatx8*)(s + base);
  bf16x8 o;
  #pragma unroll
  for (int j = 0; j < 8; ++j) o[j] = (bf16)w[j];
  *(bf16x8*)(d + base) = o;
}

// ---------------- prep: token-shift mix for all three branches in ONE x pass ----
__global__ __launch_bounds__(256) void prep3(
    const float* __restrict__ x, const float* __restrict__ ma, const float* __restrict__ mb,
    const float* __restrict__ mc,
    bf16* __restrict__ oa, bf16* __restrict__ ob, bf16* __restrict__ oc)
{
  size_t base = ((size_t)blockIdx.x * 256 + threadIdx.x) * 8;
  int d = (int)(base & (size_t)(Dd - 1));
  int l = (int)((base / Dd) & (size_t)(Ll - 1));
  floatx8 xc = *(const floatx8*)(x + base);
  floatx8 xp = l ? *(const floatx8*)(x + base - Dd) : (floatx8)(0.0f);
  floatx8 a = *(const floatx8*)(ma + d);
  floatx8 b = *(const floatx8*)(mb + d);
  floatx8 c = *(const floatx8*)(mc + d);
  bf16x8 ra, rb, rc;
  #pragma unroll
  for (int j = 0; j < 8; ++j) {
    ra[j] = (bf16)(xc[j] * a[j] + xp[j] * (1.0f - a[j]));
    rb[j] = (bf16)(xc[j] * b[j] + xp[j] * (1.0f - b[j]));
    rc[j] = (bf16)(xc[j] * c[j] + xp[j] * (1.0f - c[j]));
  }
  *(bf16x8*)(oa + base) = ra;
  *(bf16x8*)(ob + base) = rb;
  *(bf16x8*)(oc + base) = rc;
}

// ---------------- GEMM: 256x256 tile, BK=32, 8 waves, register-pipelined ----------------
// C[m,n] = sum_k A[m,k]*W[n,k]; A,W bf16.
// Key change vs R3: ds_reads for MFMA cluster k+1 issue in the SAME inter-barrier
// segment as MFMA cluster k (separate reg sets) -> LDS pipe overlaps matrix pipe.
// 2 phases per K-tile (BK=32, 1 ksub), ONE barrier per phase, triple-buffered LDS
// (3 x 32KB slots), 1 counted vmcnt per K-tile, setprio around MFMA, SGB pins
// DS_READ cluster before MFMA cluster so the prefetch can't sink.
//   P0(t): bar; stage A(t+2)->slot(t+2)%3; read a47(t); MFMA a03(t) x b(t)
//   P1(t): vmcnt(2); bar; stage B(t+2); read a03(t+1)+b(t+1); MFMA a47(t) x b(t)
// vmcnt ledger (per wave, 2 loads/stage): entering P0(t): [A(t+1),B(t+1)]=4;
//   P0 stages A(t+2)->6; P1 vmcnt(2) retires A(t+1),B(t+1) (staged 2-3 phases ago,
//   needed by this phase's reads) -> 2; stage B(t+2)->4. Never drains to 0.
// WAR: stage into slot(t+2)%3 (= tile t-1's slot) issues post-barrier at P0(t);
//   every wave drained its tile-(t-1) reads (lgkm before MFMA P1(t-1)) before that
//   barrier -> safe.
// LDS swizzle (BK=32: 4 x 16B units/row): unit' = cu ^ ((row>>1)&3); linear DMA dest,
// global source column pre-swizzled with the same involution; 8 lanes/bank-quad = min.
template <int ACT>
__global__ __launch_bounds__(512, 2) void gemm8(
    const bf16* __restrict__ A, const bf16* __restrict__ W, void* __restrict__ Cout)
{
  __shared__ __align__(16) bf16 sm[49152];   // 96 KiB: 3 slots x (A 8192 | B 8192)
  const int tid  = threadIdx.x;
  const int lane = tid & 63;
  const int w    = tid >> 6;              // 0..7
  const int wm   = (w >> 2) * 128;        // 2 warps along M
  const int wn   = (w & 3) * 64;          // 4 warps along N
  const int fr   = lane & 15;
  const int cu   = lane >> 4;             // 0..3
  const int soff = ((cu ^ ((fr >> 1) & 3)) << 3);  // swizzled 16B-unit, elems
  const int aro  = wm + fr;
  const int bro  = wn + fr;

  // XCD-bijective swizzle: 256 blocks, 8 XCDs, chunk 32
  const int flat = (int)(blockIdx.y * 4 + blockIdx.x);
  const int nid  = (flat & 7) * 32 + (flat >> 3);
  const int m0   = (nid >> 2) * 256, n0 = (nid & 3) * 256;

  // staging: per operand tile 256 rows x 32 cols = 1024 16B units; thread covers u0,u1
  const int u0 = tid, u1 = tid + 512;
  const int r0 = u0 >> 2, c0 = (((u0 & 3) ^ ((r0 >> 1) & 3)) << 3);
  const int r1 = u1 >> 2, c1 = (((u1 & 3) ^ ((r1 >> 1) & 3)) << 3);
  const size_t gA0 = (size_t)(m0 + r0) * Dd + c0;
  const size_t gA1 = (size_t)(m0 + r1) * Dd + c1;
  const size_t gB0 = (size_t)(n0 + r0) * Dd + c0;
  const size_t gB1 = (size_t)(n0 + r1) * Dd + c1;

  auto stageA = [&](int slot, int t) {
    const size_t k = (size_t)(t > 31 ? 31 : t) * 32;   // clamp tail (dup of last tile)
    bf16* d = sm + slot * 16384;
    gld16(A + gA0 + k, d + (size_t)u0 * 8);
    gld16(A + gA1 + k, d + (size_t)u1 * 8);
  };
  auto stageB = [&](int slot, int t) {
    const size_t k = (size_t)(t > 31 ? 31 : t) * 32;
    bf16* d = sm + slot * 16384 + 8192;
    gld16(W + gB0 + k, d + (size_t)u0 * 8);
    gld16(W + gB1 + k, d + (size_t)u1 * 8);
  };
  auto rdA = [&](int slot, int fi, bf16x8 (&dst)[4]) {
    const bf16* s = sm + slot * 16384;
    #pragma unroll
    for (int i = 0; i < 4; ++i)
      dst[i] = *(const bf16x8*)(s + (aro + (fi + i) * 16) * 32 + soff);
  };
  auto rdB = [&](int slot, bf16x8 (&dst)[4]) {
    const bf16* s = sm + slot * 16384 + 8192;
    #pragma unroll
    for (int j = 0; j < 4; ++j)
      dst[j] = *(const bf16x8*)(s + (bro + j * 16) * 32 + soff);
  };

  floatx4 acc[8][4];
  #pragma unroll
  for (int i = 0; i < 8; ++i)
    #pragma unroll
    for (int j = 0; j < 4; ++j)
      acc[i][j] = (floatx4)(0.0f);

  bf16x8 a03[4], a47[4], bA[4], bB[4];

  // prologue: stage tiles 0,1; retire tile 0; load first MFMA operands
  stageA(0, 0); stageB(0, 0); stageA(1, 1); stageB(1, 1);
  asm volatile("s_waitcnt vmcnt(4)" ::: "memory");
  bar();
  rdA(0, 0, a03);
  rdB(0, bA);

  int s_cur = 0, s_nxt = 1, s_stg = 2;

#define PHASE_PAIR(T, BCUR, BNXT)                                              \
  {                                                                            \
    /* P0 */                                                                   \
    bar();                                                                     \
    stageA(s_stg, (T) + 2);                                                    \
    rdA(s_cur, 4, a47);                                                        \
    __builtin_amdgcn_sched_group_barrier(0x100, 4, 0);                         \
    __builtin_amdgcn_sched_group_barrier(0x008, 16, 0);                        \
    __builtin_amdgcn_s_setprio(1);                                             \
    _Pragma("unroll") for (int i = 0; i < 4; ++i)                              \
      _Pragma("unroll") for (int j = 0; j < 4; ++j)                            \
        acc[i][j] = __builtin_amdgcn_mfma_f32_16x16x32_bf16(                   \
            a03[i], BCUR[j], acc[i][j], 0, 0, 0);                              \
    __builtin_amdgcn_s_setprio(0);                                             \
    /* P1 */                                                                   \
    asm volatile("s_waitcnt vmcnt(2)" ::: "memory");                           \
    bar();                                                                     \
    stageB(s_stg, (T) + 2);                                                    \
    rdA(s_nxt, 0, a03);                                                        \
    rdB(s_nxt, BNXT);                                                          \
    __builtin_amdgcn_sched_group_barrier(0x100, 8, 0);                         \
    __builtin_amdgcn_sched_group_barrier(0x008, 16, 0);                        \
    __builtin_amdgcn_s_setprio(1);                                             \
    _Pragma("unroll") for (int i = 0; i < 4; ++i)                              \
      _Pragma("unroll") for (int j = 0; j < 4; ++j)                            \
        acc[4 + i][j] = __builtin_amdgcn_mfma_f32_16x16x32_bf16(               \
            a47[i], BCUR[j], acc[4 + i][j], 0, 0, 0);                          \
    __builtin_amdgcn_s_setprio(0);                                             \
    { int _t = s_cur; s_cur = s_nxt; s_nxt = s_stg; s_stg = _t; }              \
  }

  for (int tt = 0; tt < 16; ++tt) {
    PHASE_PAIR(2 * tt,     bA, bB);   // even tile: use bA, prefetch into bB
    PHASE_PAIR(2 * tt + 1, bB, bA);   // odd tile:  use bB, prefetch into bA
  }
#undef PHASE_PAIR

  asm volatile("s_waitcnt vmcnt(0)" ::: "memory");

  // epilogue: C/D layout col = lane&15, row = (lane>>4)*4 + reg
  #pragma unroll
  for (int mi = 0; mi < 8; ++mi) {
    int rbase = m0 + wm + mi * 16 + (lane >> 4) * 4;
    #pragma unroll
    for (int j = 0; j < 4; ++j) {
      int col = n0 + wn + j * 16 + (lane & 15);
      #pragma unroll
      for (int r = 0; r < 4; ++r) {
        float v = acc[mi][j][r];
        size_t off = (size_t)(rbase + r) * Dd + col;
        if (ACT == 0)      ((float*)Cout)[off] = v;
        else if (ACT == 1) ((bf16*)Cout)[off]  = (bf16)(1.0f / (1.0f + __expf(-v)));
        else               ((bf16*)Cout)[off]  = (bf16)v;
      }
    }
  }
}

// ---------------- WKV chunked scan (k, v bf16) ----------------
__global__ __launch_bounds__(256) void scan_partial(
    const bf16* __restrict__ k, const bf16* __restrict__ v,
    const float* __restrict__ td, float* __restrict__ Pa, float* __restrict__ Pb)
{
  int d = blockIdx.x * 256 + threadIdx.x;
  int b = blockIdx.y, c = blockIdx.z;
  float decay = __expf(-__expf(td[d]));
  size_t base = ((size_t)(b * Ll + c * CT)) * Dd + d;
  float pa = 0.0f, pb = 0.0f;
  #pragma unroll 4
  for (int t = 0; t < CT; ++t) {
    size_t idx = base + (size_t)t * Dd;
    float ek = __expf((float)k[idx]);
    pa = decay * pa + ek * (float)v[idx];
    pb = decay * pb + ek;
  }
  size_t o = ((size_t)(b * NC + c)) * Dd + d;
  Pa[o] = pa; Pb[o] = pb;
}

__global__ __launch_bounds__(256) void scan_combine(
    const float* __restrict__ td, const float* __restrict__ Pa, const float* __restrict__ Pb,
    float* __restrict__ A0, float* __restrict__ B0)
{
  int d = blockIdx.x * 256 + threadIdx.x;
  int b = blockIdx.y;
  float dT = __expf(-__expf(td[d]) * (float)CT);   // decay^CT
  float a = 0.0f, bb = 0.0f;
  for (int c = 0; c < NC; ++c) {
    size_t o = ((size_t)(b * NC + c)) * Dd + d;
    A0[o] = a; B0[o] = bb;
    a  = dT * a  + Pa[o];
    bb = dT * bb + Pb[o];
  }
}

// y written IN-PLACE over v (thread-local read-before-write at identical index)
__global__ __launch_bounds__(256) void scan_final(
    const bf16* __restrict__ k, bf16* __restrict__ vy, const bf16* __restrict__ r,
    const float* __restrict__ td, const float* __restrict__ tf,
    const float* __restrict__ A0, const float* __restrict__ B0)
{
  int d = blockIdx.x * 256 + threadIdx.x;
  int b = blockIdx.y, c = blockIdx.z;
  float decay = __expf(-__expf(td[d]));
  float u     = tf[d];
  size_t o = ((size_t)(b * NC + c)) * Dd + d;
  float a = A0[o], bb = B0[o];
  size_t base = ((size_t)(b * Ll + c * CT)) * Dd + d;
  for (int t = 0; t < CT; ++t) {
    size_t idx = base + (size_t)t * Dd;
    float kk = (float)k[idx];
    float vv = (float)vy[idx];
    float eku = __expf(u + kk);
    float wkv = (a + eku * vv) / fmaxf(bb + eku, 1e-6f);
    vy[idx] = (bf16)((float)r[idx] * wkv);
    float ek = __expf(kk);
    a  = decay * a  + ek * vv;
    bb = decay * bb + ek;
  }
}

// ---------------- launch ----------------
extern "C" void kernel_launch(void* const* d_in, const int* in_sizes, int n_in,
                              void* d_out, int out_size, void* d_ws, size_t ws_size,
                              hipStream_t stream)
{
  const float* x  = (const float*)d_in[0];
  const float* td = (const float*)d_in[1];
  const float* tf = (const float*)d_in[2];
  const float* mk = (const float*)d_in[3];
  const float* mv = (const float*)d_in[4];
  const float* mr = (const float*)d_in[5];
  const float* Wk = (const float*)d_in[6];
  const float* Wv = (const float*)d_in[7];
  const float* Wr = (const float*)d_in[8];
  const float* Wo = (const float*)d_in[9];
  float* out = (float*)d_out;           // output f32 (reference dtype)

  // ws: 3 bf16 [M,D] buffers (phased) + 4 partial arrays = exactly 100 MiB
  char* ws = (char*)d_ws;
  const size_t S2 = (size_t)M * Dd * sizeof(bf16);   // 33,554,432 B
  const size_t SP = (size_t)Bb * NC * Dd;            // 262,144 elems
  bf16* buf1 = (bf16*)(ws);              // xmk -> v -> y
  bf16* buf2 = (bf16*)(ws + S2);         // xmv
  bf16* buf3 = (bf16*)(ws + 2 * S2);     // xmr -> k (bf16)
  float* Pa = (float*)(ws + 3 * S2);
  float* Pb = Pa + SP;
  float* A0 = Pb + SP;
  float* B0 = A0 + SP;

  // scratch parked in d_out (dead before the final f32 write):
  //   lower 32 MiB: sigmoid(r) bf16
  //   upper region: Wk/Wv/Wr bf16 (2 MiB each), dead after their gemms
  char* ob  = (char*)d_out;
  bf16* rr  = (bf16*)d_out;
  bf16* Wkb = (bf16*)(ob + ((size_t)32 << 20));
  bf16* Wvb = (bf16*)(ob + ((size_t)34 << 20));
  bf16* Wrb = (bf16*)(ob + ((size_t)36 << 20));
  // Wo bf16 (2 MiB) overlays Pa+Pb, which die after scan_combine
  bf16* Wob = (bf16*)Pa;

  dim3 gp((unsigned)((size_t)M * Dd / (256 * 8)));   // 8192 blocks
  dim3 gw((unsigned)((size_t)Dd * Dd / (256 * 8)));  // 512 blocks
  dim3 gg(Dd / 256, M / 256);                        // (4, 64) = 256 blocks

  convw3<<<dim3(gw.x, 3), 256, 0, stream>>>(Wk, Wv, Wr, Wkb, Wvb, Wrb);

  // ONE x pass for all three token-shift mixes
  prep3<<<gp, 256, 0, stream>>>(x, mk, mv, mr, buf1, buf2, buf3);  // xmk, xmv, xmr

  gemm8<1><<<gg, 512, 0, stream>>>(buf3, Wrb, rr);               // sigmoid(r) -> d_out lo; buf3 dead
  gemm8<2><<<gg, 512, 0, stream>>>(buf1, Wkb, buf3);             // k  (bf16)  buf1 dead
  gemm8<2><<<gg, 512, 0, stream>>>(buf2, Wvb, buf1);             // v  (bf16)  buf2 dead

  scan_partial<<<dim3(Dd / 256, Bb, NC), 256, 0, stream>>>(buf3, buf1, td, Pa, Pb);
  scan_combine<<<dim3(Dd / 256, Bb), 256, 0, stream>>>(td, Pa, Pb, A0, B0);
  convw<<<gw, 256, 0, stream>>>(Wo, Wob);                        // Pa/Pb now dead
  scan_final  <<<dim3(Dd / 256, Bb, NC), 256, 0, stream>>>(buf3, buf1, rr, td, tf, A0, B0);

  gemm8<0><<<gg, 512, 0, stream>>>(buf1, Wob, out);              // y·Wo -> d_out (f32)
}

// Round 6
// 338.295 us; speedup vs baseline: 1.0088x; 1.0088x over previous
//
#include <hip/hip_runtime.h>
#include <cstdint>
#include <cstddef>

typedef __bf16 bf16;
typedef __bf16 bf16x4 __attribute__((ext_vector_type(4)));
typedef __bf16 bf16x8 __attribute__((ext_vector_type(8)));
typedef float floatx4 __attribute__((ext_vector_type(4)));
typedef float floatx8 __attribute__((ext_vector_type(8)));
typedef unsigned int u32;

constexpr int Bb = 4, Ll = 4096, Dd = 1024;
constexpr int M  = Bb * Ll;          // 16384 rows
constexpr int NC = 64, CT = 64;      // chunks per sequence, chunk length

// async 16B global->LDS (width=16 emits global_load_lds_dwordx4)
typedef const __attribute__((address_space(1))) u32 glb_u32;
typedef __attribute__((address_space(3))) u32 lds_u32;
__device__ __forceinline__ void gld16(const bf16* g, bf16* l) {
  __builtin_amdgcn_global_load_lds((glb_u32*)g, (lds_u32*)l, 16, 0, 0);
}
// raw barrier (no vmcnt drain) + compiler memory fence
__device__ __forceinline__ void bar() {
  __builtin_amdgcn_s_barrier();
  asm volatile("" ::: "memory");
}

// ---------------- W f32 -> bf16 converts ----------------
__global__ __launch_bounds__(256) void convw(
    const float* __restrict__ W, bf16* __restrict__ Wb)
{
  size_t base = ((size_t)blockIdx.x * 256 + threadIdx.x) * 8;
  floatx8 w = *(const floatx8*)(W + base);
  bf16x8 o;
  #pragma unroll
  for (int j = 0; j < 8; ++j) o[j] = (bf16)w[j];
  *(bf16x8*)(Wb + base) = o;
}

__global__ __launch_bounds__(256) void convw3(
    const float* __restrict__ Wa, const float* __restrict__ Wbp, const float* __restrict__ Wc,
    bf16* __restrict__ oa, bf16* __restrict__ ob, bf16* __restrict__ oc)
{
  const float* s = blockIdx.y == 0 ? Wa : (blockIdx.y == 1 ? Wbp : Wc);
  bf16*        d = blockIdx.y == 0 ? oa : (blockIdx.y == 1 ? ob  : oc);
  size_t base = ((size_t)blockIdx.x * 256 + threadIdx.x) * 8;
  floatx8 w = *(const floatx8*)(s + base);
  bf16x8 o;
  #pragma unroll
  for (int j = 0; j < 8; ++j) o[j] = (bf16)w[j];
  *(bf16x8*)(d + base) = o;
}

// ---------------- prep: token-shift mix for all three branches in ONE x pass ----
__global__ __launch_bounds__(256) void prep3(
    const float* __restrict__ x, const float* __restrict__ ma, const float* __restrict__ mb,
    const float* __restrict__ mc,
    bf16* __restrict__ oa, bf16* __restrict__ ob, bf16* __restrict__ oc)
{
  size_t base = ((size_t)blockIdx.x * 256 + threadIdx.x) * 8;
  int d = (int)(base & (size_t)(Dd - 1));
  int l = (int)((base / Dd) & (size_t)(Ll - 1));
  floatx8 xc = *(const floatx8*)(x + base);
  floatx8 xp = l ? *(const floatx8*)(x + base - Dd) : (floatx8)(0.0f);
  floatx8 a = *(const floatx8*)(ma + d);
  floatx8 b = *(const floatx8*)(mb + d);
  floatx8 c = *(const floatx8*)(mc + d);
  bf16x8 ra, rb, rc;
  #pragma unroll
  for (int j = 0; j < 8; ++j) {
    ra[j] = (bf16)(xc[j] * a[j] + xp[j] * (1.0f - a[j]));
    rb[j] = (bf16)(xc[j] * b[j] + xp[j] * (1.0f - b[j]));
    rc[j] = (bf16)(xc[j] * c[j] + xp[j] * (1.0f - c[j]));
  }
  *(bf16x8*)(oa + base) = ra;
  *(bf16x8*)(ob + base) = rb;
  *(bf16x8*)(oc + base) = rc;
}

// ---------------- GEMM: 256x256 tile, BK=64, 8 waves, RACE-FIXED ledger ----------------
// C[m,n] = sum_k A[m,k]*W[n,k]; A,W bf16.
// RACE FIX vs R2/R3 schedule: every MFMA phase's ds_reads touch BOTH staged halves
// of tile t (wm=128 waves read the A-HIGH region even in "phase A"; wn>=128 waves
// read B-HIGH).  The old ledger only guaranteed the LOW halves before phase A ->
// waves could read LDS bytes whose DMA was still in flight (stale data from the
// previous dispatch; small-absmax corruption, state-dependent).  New ledger:
// ALL of tile t is resident before phase A(t):
//   phase A(t): reads a03+bl (tile t);    stage A(t+1) low+high (4 loads)
//   phase B(t): reads bh     (tile t);    stage B(t+1) low+high (4 loads)
//   phase C(t): reads a47    (tile t);    no stage
//   phase D(t): regs only;  s_waitcnt vmcnt(0)  [oldest load 3 phases old ->
//               nearly free] ; barrier  => tile t+1 fully landed before A(t+1).
// WAR: stages write the buffer holding tile t-1, whose last ds_reads completed
// before C(t-1)'s barrier, >=2 barriers before the stage issues.  Safe.
// Accumulation order over k unchanged -> bitwise-identical output.
template <int ACT>
__global__ __launch_bounds__(512, 2) void gemm8(
    const bf16* __restrict__ A, const bf16* __restrict__ W, void* __restrict__ Cout)
{
  __shared__ __align__(16) bf16 sm[65536];   // 128 KiB: [buf][ A 16384 | B 16384 ]
  const int tid  = threadIdx.x;
  const int lane = tid & 63;
  const int w    = tid >> 6;              // 0..7
  const int wm   = (w >> 2) * 128;        // 2 warps along M
  const int wn   = (w & 3) * 64;          // 4 warps along N
  const int fr   = lane & 15;
  const int cu   = lane >> 4;             // 0..3
  const int key  = fr & 7;
  const int sw0  = ((cu)     ^ key) * 8;  // swizzled elem offset, ksub=0
  const int sw1  = ((4 | cu) ^ key) * 8;  // ksub=1
  const int aro  = wm + fr;
  const int bro  = wn + fr;

  // XCD-bijective swizzle: 256 blocks, 8 XCDs, chunk 32
  const int flat = (int)(blockIdx.y * 4 + blockIdx.x);
  const int nid  = (flat & 7) * 32 + (flat >> 3);
  const int m0   = (nid >> 2) * 256, n0 = (nid & 3) * 256;

  // staging: thread covers 16B units tid and tid+512 of each 1024-unit half (16 KiB)
  const int w0_ = tid, w1_ = tid + 512;
  const int lr0 = w0_ >> 3, sc0 = ((w0_ & 7) ^ (lr0 & 7)) * 8;
  const int lr1 = w1_ >> 3, sc1 = ((w1_ & 7) ^ (lr1 & 7)) * 8;
  const size_t rA0 = (size_t)(m0 + lr0) * Dd + sc0;
  const size_t rA1 = (size_t)(m0 + lr1) * Dd + sc1;
  const size_t rB0 = (size_t)(n0 + lr0) * Dd + sc0;
  const size_t rB1 = (size_t)(n0 + lr1) * Dd + sc1;
  const size_t HSTEP = (size_t)128 * Dd;   // +128 rows (the "high" half)

  floatx4 acc[8][4];
  #pragma unroll
  for (int i = 0; i < 8; ++i)
    #pragma unroll
    for (int j = 0; j < 4; ++j)
      acc[i][j] = (floatx4)(0.0f);

  // prologue: stage ALL of tile 0; full drain; barrier -> tile 0 resident
  {
    bf16* A0 = sm;
    bf16* B0 = sm + 16384;
    gld16(A + rA0,         A0 + (size_t)w0_ * 8);
    gld16(A + rA1,         A0 + (size_t)w1_ * 8);
    gld16(A + rA0 + HSTEP, A0 + 8192 + (size_t)w0_ * 8);
    gld16(A + rA1 + HSTEP, A0 + 8192 + (size_t)w1_ * 8);
    gld16(W + rB0,         B0 + (size_t)w0_ * 8);
    gld16(W + rB1,         B0 + (size_t)w1_ * 8);
    gld16(W + rB0 + HSTEP, B0 + 8192 + (size_t)w0_ * 8);
    gld16(W + rB1 + HSTEP, B0 + 8192 + (size_t)w1_ * 8);
    asm volatile("s_waitcnt vmcnt(0)" ::: "memory");
    bar();
  }

  bf16x8 a[8], bl[4], bh[4];
  #pragma unroll 2
  for (int t = 0; t < 16; ++t) {
    const int p = t & 1;
    bf16* Ap = sm + p * 32768;
    bf16* Bp = Ap + 16384;
    bf16* Aq = sm + (p ^ 1) * 32768;
    bf16* Bq = Aq + 16384;
    const size_t kn = (size_t)((t < 15 ? t + 1 : 15) * 64);

    // ---- phase A: read a03 + bl (tile t, fully resident); stage A(t+1) lo+hi ----
    #pragma unroll
    for (int i = 0; i < 4; ++i) {
      a[i * 2 + 0] = *(const bf16x8*)(Ap + (aro + i * 16) * 64 + sw0);
      a[i * 2 + 1] = *(const bf16x8*)(Ap + (aro + i * 16) * 64 + sw1);
    }
    #pragma unroll
    for (int j = 0; j < 2; ++j) {
      bl[j * 2 + 0] = *(const bf16x8*)(Bp + (bro + j * 16) * 64 + sw0);
      bl[j * 2 + 1] = *(const bf16x8*)(Bp + (bro + j * 16) * 64 + sw1);
    }
    gld16(A + rA0 + kn,         Aq + (size_t)w0_ * 8);
    gld16(A + rA1 + kn,         Aq + (size_t)w1_ * 8);
    gld16(A + rA0 + kn + HSTEP, Aq + 8192 + (size_t)w0_ * 8);
    gld16(A + rA1 + kn + HSTEP, Aq + 8192 + (size_t)w1_ * 8);
    bar();
    __builtin_amdgcn_s_setprio(1);
    #pragma unroll
    for (int ks = 0; ks < 2; ++ks)
      #pragma unroll
      for (int i = 0; i < 4; ++i)
        #pragma unroll
        for (int j = 0; j < 2; ++j)
          acc[i][j] = __builtin_amdgcn_mfma_f32_16x16x32_bf16(a[i * 2 + ks], bl[j * 2 + ks], acc[i][j], 0, 0, 0);
    __builtin_amdgcn_s_setprio(0);
    bar();

    // ---- phase B: read bh (tile t); stage B(t+1) lo+hi ----
    #pragma unroll
    for (int j = 0; j < 2; ++j) {
      bh[j * 2 + 0] = *(const bf16x8*)(Bp + (bro + (j + 2) * 16) * 64 + sw0);
      bh[j * 2 + 1] = *(const bf16x8*)(Bp + (bro + (j + 2) * 16) * 64 + sw1);
    }
    gld16(W + rB0 + kn,         Bq + (size_t)w0_ * 8);
    gld16(W + rB1 + kn,         Bq + (size_t)w1_ * 8);
    gld16(W + rB0 + kn + HSTEP, Bq + 8192 + (size_t)w0_ * 8);
    gld16(W + rB1 + kn + HSTEP, Bq + 8192 + (size_t)w1_ * 8);
    bar();
    __builtin_amdgcn_s_setprio(1);
    #pragma unroll
    for (int ks = 0; ks < 2; ++ks)
      #pragma unroll
      for (int i = 0; i < 4; ++i)
        #pragma unroll
        for (int j = 0; j < 2; ++j)
          acc[i][j + 2] = __builtin_amdgcn_mfma_f32_16x16x32_bf16(a[i * 2 + ks], bh[j * 2 + ks], acc[i][j + 2], 0, 0, 0);
    __builtin_amdgcn_s_setprio(0);
    bar();

    // ---- phase C: read a47 (tile t); no stage ----
    #pragma unroll
    for (int i = 0; i < 4; ++i) {
      a[i * 2 + 0] = *(const bf16x8*)(Ap + (aro + (i + 4) * 16) * 64 + sw0);
      a[i * 2 + 1] = *(const bf16x8*)(Ap + (aro + (i + 4) * 16) * 64 + sw1);
    }
    bar();
    __builtin_amdgcn_s_setprio(1);
    #pragma unroll
    for (int ks = 0; ks < 2; ++ks)
      #pragma unroll
      for (int i = 0; i < 4; ++i)
        #pragma unroll
        for (int j = 0; j < 2; ++j)
          acc[i + 4][j + 2] = __builtin_amdgcn_mfma_f32_16x16x32_bf16(a[i * 2 + ks], bh[j * 2 + ks], acc[i + 4][j + 2], 0, 0, 0);
    __builtin_amdgcn_s_setprio(0);
    bar();

    // ---- phase D: regs only; drain tile t+1 (oldest load 3 phases old) ----
    asm volatile("s_waitcnt vmcnt(0)" ::: "memory");
    bar();
    __builtin_amdgcn_s_setprio(1);
    #pragma unroll
    for (int ks = 0; ks < 2; ++ks)
      #pragma unroll
      for (int i = 0; i < 4; ++i)
        #pragma unroll
        for (int j = 0; j < 2; ++j)
          acc[i + 4][j] = __builtin_amdgcn_mfma_f32_16x16x32_bf16(a[i * 2 + ks], bl[j * 2 + ks], acc[i + 4][j], 0, 0, 0);
    __builtin_amdgcn_s_setprio(0);
    bar();
  }
  asm volatile("s_waitcnt vmcnt(0)" ::: "memory");

  // epilogue: C/D layout col = lane&15, row = (lane>>4)*4 + reg
  #pragma unroll
  for (int mi = 0; mi < 8; ++mi) {
    int rbase = m0 + wm + mi * 16 + (lane >> 4) * 4;
    #pragma unroll
    for (int j = 0; j < 4; ++j) {
      int col = n0 + wn + j * 16 + (lane & 15);
      #pragma unroll
      for (int r = 0; r < 4; ++r) {
        float v = acc[mi][j][r];
        size_t off = (size_t)(rbase + r) * Dd + col;
        if (ACT == 0)      ((float*)Cout)[off] = v;
        else if (ACT == 1) ((bf16*)Cout)[off]  = (bf16)(1.0f / (1.0f + __expf(-v)));
        else               ((bf16*)Cout)[off]  = (bf16)v;
      }
    }
  }
}

// ---------------- WKV chunked scan — VECTORIZED 4 ch/thread (bf16x4 = 8B/lane) ----
// grid = Bb*NC blocks (one per (b,c) chunk), 256 threads, d0 = tid*4.
// Identical per-channel op order as scalar version -> bitwise-identical output.
__global__ __launch_bounds__(256) void scan_partial(
    const bf16* __restrict__ k, const bf16* __restrict__ v,
    const float* __restrict__ td, float* __restrict__ Pa, float* __restrict__ Pb)
{
  const int pair = blockIdx.x;            // b*NC + c
  const int b = pair >> 6, c = pair & (NC - 1);
  const int d0 = threadIdx.x * 4;
  floatx4 tdv = *(const floatx4*)(td + d0);
  float decay[4], pa[4], pb[4];
  #pragma unroll
  for (int j = 0; j < 4; ++j) {
    decay[j] = __expf(-__expf(tdv[j]));
    pa[j] = 0.0f; pb[j] = 0.0f;
  }
  size_t base = ((size_t)(b * Ll + c * CT)) * Dd + d0;
  #pragma unroll 4
  for (int t = 0; t < CT; ++t) {
    size_t idx = base + (size_t)t * Dd;
    bf16x4 kk = *(const bf16x4*)(k + idx);
    bf16x4 vv = *(const bf16x4*)(v + idx);
    #pragma unroll
    for (int j = 0; j < 4; ++j) {
      float ek = __expf((float)kk[j]);
      pa[j] = decay[j] * pa[j] + ek * (float)vv[j];
      pb[j] = decay[j] * pb[j] + ek;
    }
  }
  size_t o = (size_t)pair * Dd + d0;
  floatx4 outa, outb;
  #pragma unroll
  for (int j = 0; j < 4; ++j) { outa[j] = pa[j]; outb[j] = pb[j]; }
  *(floatx4*)(Pa + o) = outa;
  *(floatx4*)(Pb + o) = outb;
}

__global__ __launch_bounds__(256) void scan_combine(
    const float* __restrict__ td, const float* __restrict__ Pa, const float* __restrict__ Pb,
    float* __restrict__ A0, float* __restrict__ B0)
{
  int d = blockIdx.x * 256 + threadIdx.x;
  int b = blockIdx.y;
  float dT = __expf(-__expf(td[d]) * (float)CT);   // decay^CT
  float a = 0.0f, bb = 0.0f;
  for (int c = 0; c < NC; ++c) {
    size_t o = ((size_t)(b * NC + c)) * Dd + d;
    A0[o] = a; B0[o] = bb;
    a  = dT * a  + Pa[o];
    bb = dT * bb + Pb[o];
  }
}

// y written IN-PLACE over v (thread-local read-before-write at identical index)
__global__ __launch_bounds__(256) void scan_final(
    const bf16* __restrict__ k, bf16* __restrict__ vy, const bf16* __restrict__ r,
    const float* __restrict__ td, const float* __restrict__ tf,
    const float* __restrict__ A0, const float* __restrict__ B0)
{
  const int pair = blockIdx.x;            // b*NC + c
  const int b = pair >> 6, c = pair & (NC - 1);
  const int d0 = threadIdx.x * 4;
  floatx4 tdv = *(const floatx4*)(td + d0);
  floatx4 tfv = *(const floatx4*)(tf + d0);
  size_t o = (size_t)pair * Dd + d0;
  floatx4 av = *(const floatx4*)(A0 + o);
  floatx4 bv = *(const floatx4*)(B0 + o);
  float decay[4], u[4], a[4], bb[4];
  #pragma unroll
  for (int j = 0; j < 4; ++j) {
    decay[j] = __expf(-__expf(tdv[j]));
    u[j] = tfv[j]; a[j] = av[j]; bb[j] = bv[j];
  }
  size_t base = ((size_t)(b * Ll + c * CT)) * Dd + d0;
  #pragma unroll 2
  for (int t = 0; t < CT; ++t) {
    size_t idx = base + (size_t)t * Dd;
    bf16x4 kk = *(const bf16x4*)(k + idx);
    bf16x4 vv = *(const bf16x4*)(vy + idx);
    bf16x4 rr4 = *(const bf16x4*)(r + idx);
    bf16x4 y;
    #pragma unroll
    for (int j = 0; j < 4; ++j) {
      float kkj = (float)kk[j];
      float vvj = (float)vv[j];
      float eku = __expf(u[j] + kkj);
      float wkv = (a[j] + eku * vvj) / fmaxf(bb[j] + eku, 1e-6f);
      y[j] = (bf16)((float)rr4[j] * wkv);
      float ek = __expf(kkj);
      a[j]  = decay[j] * a[j]  + ek * vvj;
      bb[j] = decay[j] * bb[j] + ek;
    }
    *(bf16x4*)(vy + idx) = y;
  }
}

// ---------------- launch ----------------
extern "C" void kernel_launch(void* const* d_in, const int* in_sizes, int n_in,
                              void* d_out, int out_size, void* d_ws, size_t ws_size,
                              hipStream_t stream)
{
  const float* x  = (const float*)d_in[0];
  const float* td = (const float*)d_in[1];
  const float* tf = (const float*)d_in[2];
  const float* mk = (const float*)d_in[3];
  const float* mv = (const float*)d_in[4];
  const float* mr = (const float*)d_in[5];
  const float* Wk = (const float*)d_in[6];
  const float* Wv = (const float*)d_in[7];
  const float* Wr = (const float*)d_in[8];
  const float* Wo = (const float*)d_in[9];
  float* out = (float*)d_out;           // output f32 (reference dtype)

  // ws: 3 bf16 [M,D] buffers (phased) + 4 partial arrays = exactly 100 MiB
  char* ws = (char*)d_ws;
  const size_t S2 = (size_t)M * Dd * sizeof(bf16);   // 33,554,432 B
  const size_t SP = (size_t)Bb * NC * Dd;            // 262,144 elems
  bf16* buf1 = (bf16*)(ws);              // xmk -> v -> y
  bf16* buf2 = (bf16*)(ws + S2);         // xmv
  bf16* buf3 = (bf16*)(ws + 2 * S2);     // xmr -> k (bf16)
  float* Pa = (float*)(ws + 3 * S2);
  float* Pb = Pa + SP;
  float* A0 = Pb + SP;
  float* B0 = A0 + SP;

  // scratch parked in d_out (dead before the final f32 write):
  //   lower 32 MiB: sigmoid(r) bf16
  //   upper region: Wk/Wv/Wr bf16 (2 MiB each), dead after their gemms
  char* ob  = (char*)d_out;
  bf16* rr  = (bf16*)d_out;
  bf16* Wkb = (bf16*)(ob + ((size_t)32 << 20));
  bf16* Wvb = (bf16*)(ob + ((size_t)34 << 20));
  bf16* Wrb = (bf16*)(ob + ((size_t)36 << 20));
  // Wo bf16 (2 MiB) overlays Pa+Pb, which die after scan_combine
  bf16* Wob = (bf16*)Pa;

  dim3 gp((unsigned)((size_t)M * Dd / (256 * 8)));   // 8192 blocks
  dim3 gw((unsigned)((size_t)Dd * Dd / (256 * 8)));  // 512 blocks
  dim3 gg(Dd / 256, M / 256);                        // (4, 64) = 256 blocks

  convw3<<<dim3(gw.x, 3), 256, 0, stream>>>(Wk, Wv, Wr, Wkb, Wvb, Wrb);

  // ONE x pass for all three token-shift mixes
  prep3<<<gp, 256, 0, stream>>>(x, mk, mv, mr, buf1, buf2, buf3);  // xmk, xmv, xmr

  gemm8<1><<<gg, 512, 0, stream>>>(buf3, Wrb, rr);               // sigmoid(r) -> d_out lo; buf3 dead
  gemm8<2><<<gg, 512, 0, stream>>>(buf1, Wkb, buf3);             // k  (bf16)  buf1 dead
  gemm8<2><<<gg, 512, 0, stream>>>(buf2, Wvb, buf1);             // v  (bf16)  buf2 dead

  scan_partial<<<dim3(Bb * NC), 256, 0, stream>>>(buf3, buf1, td, Pa, Pb);
  scan_combine<<<dim3(Dd / 256, Bb), 256, 0, stream>>>(td, Pa, Pb, A0, B0);
  convw<<<gw, 256, 0, stream>>>(Wo, Wob);                        // Pa/Pb now dead
  scan_final  <<<dim3(Bb * NC), 256, 0, stream>>>(buf3, buf1, rr, td, tf, A0, B0);

  gemm8<0><<<gg, 512, 0, stream>>>(buf1, Wob, out);              // y·Wo -> d_out (f32)
}